// Round 5
// baseline (222.587 us; speedup 1.0000x reference)
//
#include <hip/hip_runtime.h>
#include <hip/hip_fp16.h>
#include <hip/hip_bf16.h>

#define N_TOT 65536
#define D_DIM 512
#define K_DIM 64
#define NC    32                // n-rows per MFMA K-step
#define GSZ   (K_DIM * D_DIM)   // 32768 elements of partial G

typedef __bf16   bf16x8 __attribute__((ext_vector_type(8)));
typedef float    f32x4  __attribute__((ext_vector_type(4)));
typedef _Float16 half8  __attribute__((ext_vector_type(8)));

union pk4 { unsigned int u[4]; bf16x8 v; };

__device__ __forceinline__ unsigned int pack2(float a, float b) {
    // HW packed convert: v_cvt_pk_bf16_f32 (RNE), replaces 12-op manual pack
    __hip_bfloat162 t = __float22bfloat162_rn(make_float2(a, b));
    union { __hip_bfloat162 h; unsigned int u; } r; r.h = t;
    return r.u;
}

// K1 (instrumented): pass A = real work (register-direct MFMA, as R4, with
// HW packed bf16 convert). pass B = discarded stream of the NEIGHBOR block's
// h-slab with the identical address pattern, kept alive by a bit-opaque
// predicate. Purpose: push k1 above the harness's 78 us ws-poison fills so
// its counter row (VALUBusy / hbm_gbps / VGPR_Count / FETCH) becomes visible
// in top-5 -- four structural rewrites moved nothing; buying data.
extern "C" __global__ void __launch_bounds__(1024)
k1_partial(const float* __restrict__ h, const float* __restrict__ F,
           float* __restrict__ trw_out, unsigned short* __restrict__ gpart,
           float* __restrict__ out, int rowsPerBlock) {
    __shared__ float red[16];

    const int tid = threadIdx.x;
    const int b   = blockIdx.x;
    if (b == 0 && tid == 0) out[0] = 0.0f;        // d_out poisoned; zero before K2

    const int wave = tid >> 6;    // 0..15 ; wave owns d in [32w, 32w+32)
    const int lane = tid & 63;
    const int m    = lane & 15;
    const int q    = lane >> 4;

    const int row0    = b * rowsPerBlock;
    const int nChunks = rowsPerBlock / NC;

    f32x4 acc[4][2];
    #pragma unroll
    for (int kt = 0; kt < 4; ++kt)
        #pragma unroll
        for (int dt = 0; dt < 2; ++dt)
            acc[kt][dt] = (f32x4){0.f, 0.f, 0.f, 0.f};

    float trw = 0.f;

    // ---------------- pass A: real work ----------------
    const float* hb = h + (size_t)(row0 + q * 8) * D_DIM + wave * 32 + m;
    const float* fb = F + (size_t)(row0 + q * 8) * K_DIM + m;

    for (int c = 0; c < nChunks; ++c) {
        // issue ALL 48 loads before any use (max MLP)
        float vb[16], va[32];
        #pragma unroll
        for (int dt = 0; dt < 2; ++dt)
            #pragma unroll
            for (int j = 0; j < 8; ++j)
                vb[dt * 8 + j] = hb[(size_t)j * D_DIM + dt * 16];
        #pragma unroll
        for (int kk = 0; kk < 4; ++kk)
            #pragma unroll
            for (int j = 0; j < 8; ++j)
                va[kk * 8 + j] = fb[(size_t)j * K_DIM + kk * 16];

        bf16x8 bfrag[2], afrag[4];
        #pragma unroll
        for (int dt = 0; dt < 2; ++dt) {
            pk4 p;
            #pragma unroll
            for (int jj = 0; jj < 4; ++jj) {
                float a0 = vb[dt * 8 + 2 * jj], a1 = vb[dt * 8 + 2 * jj + 1];
                trw += a0 * a0 + a1 * a1;
                p.u[jj] = pack2(a0, a1);
            }
            bfrag[dt] = p.v;
        }
        #pragma unroll
        for (int kk = 0; kk < 4; ++kk) {
            pk4 p;
            #pragma unroll
            for (int jj = 0; jj < 4; ++jj)
                p.u[jj] = pack2(va[kk * 8 + 2 * jj], va[kk * 8 + 2 * jj + 1]);
            afrag[kk] = p.v;
        }

        #pragma unroll
        for (int kt = 0; kt < 4; ++kt)
            #pragma unroll
            for (int dt = 0; dt < 2; ++dt)
                acc[kt][dt] = __builtin_amdgcn_mfma_f32_16x16x32_bf16(
                    afrag[kt], bfrag[dt], acc[kt][dt], 0, 0, 0);

        hb += (size_t)NC * D_DIM;
        fb += (size_t)NC * K_DIM;
    }

    // ---------------- pass B: discarded neighbor-slab stream ----------------
    // Same address pattern, different slab (so it can't be an L1 hit of pass
    // A's own lines). Result folded through an opaque-false predicate.
    {
        const int bn2 = (b + 1) & 255;
        const float* hb2 = h + (size_t)(bn2 * rowsPerBlock + q * 8) * D_DIM
                             + wave * 32 + m;
        float trw2 = 0.f;
        for (int c = 0; c < nChunks; ++c) {
            float v2[16];
            #pragma unroll
            for (int dt = 0; dt < 2; ++dt)
                #pragma unroll
                for (int j = 0; j < 8; ++j)
                    v2[dt * 8 + j] = hb2[(size_t)j * D_DIM + dt * 16];
            #pragma unroll
            for (int i = 0; i < 16; ++i) trw2 += v2[i] * v2[i];
            hb2 += (size_t)NC * D_DIM;
        }
        union { float f; unsigned int u; } tw; tw.f = trw2;
        if ((tw.u ^ 0xAAAAAAAAu) == 0x12345u)   // opaque-false: keeps pass B live
            trw += trw2;
    }

    // ---- epilogue: partial G -> fp16 in workspace ----
    unsigned short* gp = gpart + (size_t)b * GSZ;
    #pragma unroll
    for (int kt = 0; kt < 4; ++kt)
        #pragma unroll
        for (int dt = 0; dt < 2; ++dt)
            #pragma unroll
            for (int r = 0; r < 4; ++r) {
                const int k = kt * 16 + q * 4 + r;      // C/D row = (lane>>4)*4 + reg
                const int d = wave * 32 + dt * 16 + m;  // C/D col = lane&15
                __half hv = __float2half(acc[kt][dt][r]);
                gp[k * D_DIM + d] = *(unsigned short*)&hv;
            }

    // ---- tr_wtw partial: wave shuffle reduce -> LDS -> one store ----
    #pragma unroll
    for (int off = 32; off > 0; off >>= 1) trw += __shfl_down(trw, off, 64);
    if (lane == 0) red[wave] = trw;
    __syncthreads();
    if (tid == 0) {
        float s = 0.f;
        #pragma unroll
        for (int w = 0; w < 16; ++w) s += red[w];
        trw_out[b] = s;
    }
}

// K2: out = sum_b trw[b] - sum_{k,d} (sum_b Gpart[b][k,d])^2   (256 blocks)
extern "C" __global__ void __launch_bounds__(512)
k2_reduce(const float* __restrict__ trw, const unsigned short* __restrict__ gpart,
          float* __restrict__ out, int P) {
    __shared__ float sh[32 * 16 * 8];   // 16 KB: [sub][oct][j]
    __shared__ float red2[8];

    const int tid = threadIdx.x;
    const int sub = tid >> 4;                  // 0..31 : b-split
    const int oct = tid & 15;
    const int tt  = blockIdx.x * 16 + oct;     // 0..4095 ; elements 8tt..8tt+7

    float g[8];
    #pragma unroll
    for (int j = 0; j < 8; ++j) g[j] = 0.f;

    const unsigned short* base = gpart + (size_t)tt * 8;
    for (int b = sub; b < P; b += 32) {
        half8 v = *(const half8*)(base + (size_t)b * GSZ);
        #pragma unroll
        for (int j = 0; j < 8; ++j) g[j] += (float)v[j];
    }
    #pragma unroll
    for (int j = 0; j < 8; ++j) sh[(sub * 16 + oct) * 8 + j] = g[j];
    __syncthreads();

    float val = 0.f;
    if (tid < 128) {
        const int o2 = tid >> 3, j = tid & 7;
        float s = 0.f;
        #pragma unroll
        for (int sb = 0; sb < 32; ++sb) s += sh[(sb * 16 + o2) * 8 + j];
        val = -s * s;
    } else if (blockIdx.x == 0 && tid - 128 < P) {
        val = trw[tid - 128];                  // fold tr_wtw partials in block 0
    }

    #pragma unroll
    for (int off = 32; off > 0; off >>= 1) val += __shfl_down(val, off, 64);
    if ((tid & 63) == 0) red2[tid >> 6] = val;
    __syncthreads();
    if (tid == 0) {
        float s = 0.f;
        #pragma unroll
        for (int w = 0; w < 8; ++w) s += red2[w];
        atomicAdd(out, s);
    }
}

extern "C" void kernel_launch(void* const* d_in, const int* in_sizes, int n_in,
                              void* d_out, int out_size, void* d_ws, size_t ws_size,
                              hipStream_t stream) {
    const float* h = (const float*)d_in[0];   // [65536, 512]
    const float* F = (const float*)d_in[1];   // [65536, 64]
    float* out = (float*)d_out;

    // ws layout: [0,4096): trw fp32 (P<=256) ; [4096, 4096+P*64KiB): fp16 partial G
    int P = 256;
    while (P > 1 && (size_t)4096 + (size_t)P * (GSZ * 2) > ws_size) P >>= 1;
    const int rowsPerBlock = N_TOT / P;

    float* trw = (float*)d_ws;
    unsigned short* gpart = (unsigned short*)((char*)d_ws + 4096);

    hipLaunchKernelGGL(k1_partial, dim3(P), dim3(1024), 0, stream,
                       h, F, trw, gpart, out, rowsPerBlock);
    hipLaunchKernelGGL(k2_reduce, dim3(256), dim3(512), 0, stream,
                       trw, gpart, out, P);
}

// Round 6
// 213.543 us; speedup vs baseline: 1.0424x; 1.0424x over previous
//
#include <hip/hip_runtime.h>
#include <hip/hip_fp16.h>
#include <hip/hip_bf16.h>

#define N_TOT 65536
#define D_DIM 512
#define K_DIM 64
#define NC    32                // n-rows per chunk (one MFMA K=32 step)
#define GSZ   (K_DIM * D_DIM)   // 32768 elements of partial G

typedef __bf16   bf16x8 __attribute__((ext_vector_type(8)));
typedef float    f32x4  __attribute__((ext_vector_type(4)));
typedef _Float16 half8  __attribute__((ext_vector_type(8)));

union pk4 { unsigned int u[4]; bf16x8 v; };

__device__ __forceinline__ unsigned int pack2(float a, float b) {
    __hip_bfloat162 t = __float22bfloat162_rn(make_float2(a, b));
    union { __hip_bfloat162 h; unsigned int u; } r; r.h = t;
    return r.u;
}

typedef __attribute__((address_space(3))) void       lds_void;
typedef __attribute__((address_space(1))) const void gbl_void;

// async DMA global->LDS, 16 B per lane; LDS dest = wave-uniform base + lane*16
__device__ __forceinline__ void dma16(const float* g, float* l) {
    __builtin_amdgcn_global_load_lds((gbl_void*)g, (lds_void*)l, 16, 0, 0);
}

// K1: global_load_lds staging (m97 pattern). R5 counters showed VGPR=56 had
// register-batched the direct loads into serial vmcnt(0) chains (VALUBusy 12%,
// MfmaUtil 2%, 2.3 TB/s latency-bound). DMA staging needs no VGPR
// destinations: whole 72 KB chunk in flight, one barrier per chunk.
extern "C" __global__ void __launch_bounds__(1024)
k1_partial(const float* __restrict__ h, const float* __restrict__ F,
           float* __restrict__ trw_out, unsigned short* __restrict__ gpart,
           float* __restrict__ out, int rowsPerBlock) {
    __shared__ float hbuf[2][NC][D_DIM];   // 2 x 64 KB, fp32, [n][d]
    __shared__ float fbuf[2][NC][K_DIM];   // 2 x  8 KB, fp32, [n][k]
    __shared__ float red[16];

    const int tid = threadIdx.x;
    const int b   = blockIdx.x;
    if (b == 0 && tid == 0) out[0] = 0.0f;        // d_out poisoned; zero before K2

    const int wave = tid >> 6;    // 0..15 ; wave owns d in [32w, 32w+32)
    const int lane = tid & 63;
    const int m    = lane & 15;
    const int q    = lane >> 4;

    const int row0    = b * rowsPerBlock;
    const int nChunks = rowsPerBlock / NC;

    f32x4 acc[4][2];
    #pragma unroll
    for (int kt = 0; kt < 4; ++kt)
        #pragma unroll
        for (int dt = 0; dt < 2; ++dt)
            acc[kt][dt] = (f32x4){0.f, 0.f, 0.f, 0.f};

    float trw = 0.f;

    // stage chunk c into buffer p: wave w DMAs h-rows 2w,2w+1 (2 KB each, two
    // 1 KB halves); waves 0..7 DMA 4 F-rows each (1 KB).
    auto stage = [&](int c, int p) {
        const int r0 = row0 + c * NC;
        const float* g = h + (size_t)(r0 + 2 * wave) * D_DIM + lane * 4;
        #pragma unroll
        for (int rr = 0; rr < 2; ++rr)
            #pragma unroll
            for (int hf = 0; hf < 2; ++hf)
                dma16(g + rr * D_DIM + hf * 256, &hbuf[p][2 * wave + rr][hf * 256]);
        if (wave < 8) {
            const float* gf = F + (size_t)(r0 + 4 * wave) * K_DIM + lane * 4;
            dma16(gf, &fbuf[p][4 * wave][0]);
        }
    };

    stage(0, 0);

    for (int c = 0; c < nChunks; ++c) {
        __syncthreads();                          // DMA(c) landed; buf[(c+1)&1] free
        if (c + 1 < nChunks) stage(c + 1, (c + 1) & 1);

        const int p = c & 1;
        bf16x8 bfrag[2], afrag[4];
        // B: h fragment  B[d=lane&15][j over n] = hbuf[q*8+j][w*32+dt*16+m]
        #pragma unroll
        for (int dt = 0; dt < 2; ++dt) {
            float v[8];
            #pragma unroll
            for (int j = 0; j < 8; ++j) {
                v[j] = hbuf[p][q * 8 + j][wave * 32 + dt * 16 + m];
                trw += v[j] * v[j];               // each (n,d) touched once/block
            }
            pk4 pp;
            #pragma unroll
            for (int jj = 0; jj < 4; ++jj) pp.u[jj] = pack2(v[2*jj], v[2*jj+1]);
            bfrag[dt] = pp.v;
        }
        // A: F fragment  A[k=lane&15][j over n] = fbuf[q*8+j][kt*16+m]
        #pragma unroll
        for (int kt = 0; kt < 4; ++kt) {
            float v[8];
            #pragma unroll
            for (int j = 0; j < 8; ++j)
                v[j] = fbuf[p][q * 8 + j][kt * 16 + m];
            pk4 pp;
            #pragma unroll
            for (int jj = 0; jj < 4; ++jj) pp.u[jj] = pack2(v[2*jj], v[2*jj+1]);
            afrag[kt] = pp.v;
        }

        #pragma unroll
        for (int kt = 0; kt < 4; ++kt)
            #pragma unroll
            for (int dt = 0; dt < 2; ++dt)
                acc[kt][dt] = __builtin_amdgcn_mfma_f32_16x16x32_bf16(
                    afrag[kt], bfrag[dt], acc[kt][dt], 0, 0, 0);
    }

    // ---- epilogue: partial G -> fp16 in workspace ----
    unsigned short* gp = gpart + (size_t)b * GSZ;
    #pragma unroll
    for (int kt = 0; kt < 4; ++kt)
        #pragma unroll
        for (int dt = 0; dt < 2; ++dt)
            #pragma unroll
            for (int r = 0; r < 4; ++r) {
                const int k = kt * 16 + q * 4 + r;      // C/D row = (lane>>4)*4 + reg
                const int d = wave * 32 + dt * 16 + m;  // C/D col = lane&15
                __half hv = __float2half(acc[kt][dt][r]);
                gp[k * D_DIM + d] = *(unsigned short*)&hv;
            }

    // ---- tr_wtw partial: wave shuffle reduce -> LDS -> one store ----
    #pragma unroll
    for (int off = 32; off > 0; off >>= 1) trw += __shfl_down(trw, off, 64);
    if (lane == 0) red[wave] = trw;
    __syncthreads();
    if (tid == 0) {
        float s = 0.f;
        #pragma unroll
        for (int w = 0; w < 16; ++w) s += red[w];
        trw_out[b] = s;
    }
}

// K2: out = sum_b trw[b] - sum_{k,d} (sum_b Gpart[b][k,d])^2   (256 blocks)
extern "C" __global__ void __launch_bounds__(512)
k2_reduce(const float* __restrict__ trw, const unsigned short* __restrict__ gpart,
          float* __restrict__ out, int P) {
    __shared__ float sh[32 * 16 * 8];   // 16 KB: [sub][oct][j]
    __shared__ float red2[8];

    const int tid = threadIdx.x;
    const int sub = tid >> 4;                  // 0..31 : b-split
    const int oct = tid & 15;
    const int tt  = blockIdx.x * 16 + oct;     // 0..4095 ; elements 8tt..8tt+7

    float g[8];
    #pragma unroll
    for (int j = 0; j < 8; ++j) g[j] = 0.f;

    const unsigned short* base = gpart + (size_t)tt * 8;
    for (int b = sub; b < P; b += 32) {
        half8 v = *(const half8*)(base + (size_t)b * GSZ);
        #pragma unroll
        for (int j = 0; j < 8; ++j) g[j] += (float)v[j];
    }
    #pragma unroll
    for (int j = 0; j < 8; ++j) sh[(sub * 16 + oct) * 8 + j] = g[j];
    __syncthreads();

    float val = 0.f;
    if (tid < 128) {
        const int o2 = tid >> 3, j = tid & 7;
        float s = 0.f;
        #pragma unroll
        for (int sb = 0; sb < 32; ++sb) s += sh[(sb * 16 + o2) * 8 + j];
        val = -s * s;
    } else if (blockIdx.x == 0 && tid - 128 < P) {
        val = trw[tid - 128];                  // fold tr_wtw partials in block 0
    }

    #pragma unroll
    for (int off = 32; off > 0; off >>= 1) val += __shfl_down(val, off, 64);
    if ((tid & 63) == 0) red2[tid >> 6] = val;
    __syncthreads();
    if (tid == 0) {
        float s = 0.f;
        #pragma unroll
        for (int w = 0; w < 8; ++w) s += red2[w];
        atomicAdd(out, s);
    }
}

extern "C" void kernel_launch(void* const* d_in, const int* in_sizes, int n_in,
                              void* d_out, int out_size, void* d_ws, size_t ws_size,
                              hipStream_t stream) {
    const float* h = (const float*)d_in[0];   // [65536, 512]
    const float* F = (const float*)d_in[1];   // [65536, 64]
    float* out = (float*)d_out;

    // ws layout: [0,4096): trw fp32 (P<=256) ; [4096, 4096+P*64KiB): fp16 partial G
    int P = 256;
    while (P > 1 && (size_t)4096 + (size_t)P * (GSZ * 2) > ws_size) P >>= 1;
    const int rowsPerBlock = N_TOT / P;

    float* trw = (float*)d_ws;
    unsigned short* gpart = (unsigned short*)((char*)d_ws + 4096);

    hipLaunchKernelGGL(k1_partial, dim3(P), dim3(1024), 0, stream,
                       h, F, trw, gpart, out, rowsPerBlock);
    hipLaunchKernelGGL(k2_reduce, dim3(256), dim3(512), 0, stream,
                       trw, gpart, out, P);
}